// Round 7
// baseline (285.912 us; speedup 1.0000x reference)
//
#include <hip/hip_runtime.h>
#include <hip/hip_fp16.h>
#include <math.h>

// Problem constants (fixed by the reference)
#define LEN   5440          // 64*64 + 32*32 + 16*16 + 8*8
#define NTOK  21760         // B(4) * LEN
#define DFF   1024
#define LEPS  1e-5f

typedef __attribute__((ext_vector_type(8))) _Float16 f16x8;
typedef __attribute__((ext_vector_type(4))) float f32x4;

__device__ __forceinline__ float4 f4_add(float4 a, float4 b) {
    return make_float4(a.x + b.x, a.y + b.y, a.z + b.z, a.w + b.w);
}

__device__ __forceinline__ __half2 u2h2(unsigned u) {
    union { unsigned u; __half2 h; } c; c.u = u; return c.h;
}

// async global->LDS, 16B per lane; LDS dest = wave-uniform base + lane*16.
__device__ __forceinline__ void gload_lds16(const void* g, void* l) {
    __builtin_amdgcn_global_load_lds(
        (const __attribute__((address_space(1))) unsigned int*)g,
        (__attribute__((address_space(3))) unsigned int*)l, 16, 0, 0);
}

// Bijective XCD-chunk swizzle (m204).
__device__ __forceinline__ int swz8(int lin, int nwg) {
    const int q = nwg >> 3, r = nwg & 7;
    const int x = lin & 7, j = lin >> 3;
    return (x < r ? x * (q + 1) : r * (q + 1) + (x - r) * q) + j;
}

// ---------------- pack: weights -> fp16, transposed to [N][K] ----------------
__global__ __launch_bounds__(256) void pack_k(const float* __restrict__ w_off,
                                              const float* __restrict__ w_attn,
                                              const float* __restrict__ w_val,
                                              const float* __restrict__ b_off,
                                              const float* __restrict__ b_attn,
                                              const float* __restrict__ b_val,
                                              const float* __restrict__ w_out,
                                              const float* __restrict__ w1,
                                              const float* __restrict__ w2,
                                              __half* __restrict__ WcatT,
                                              __half* __restrict__ woutT,
                                              __half* __restrict__ w1T,
                                              __half* __restrict__ w2T,
                                              float* __restrict__ bcat) {
    const int i = blockIdx.x * 256 + threadIdx.x;
    if (i < 163840) {                      // WcatT [c<640][k<256]
        const int c = i >> 8, k = i & 255;
        float v;
        if (c < 256)      v = w_off[k * 256 + c];
        else if (c < 384) v = w_attn[k * 128 + (c - 256)];
        else              v = w_val[k * 256 + (c - 384)];
        WcatT[i] = __float2half(v);
    } else if (i < 229376) {               // woutT [c<256][k<256]
        const int j = i - 163840, c = j >> 8, k = j & 255;
        woutT[j] = __float2half(w_out[k * 256 + c]);
    } else if (i < 491520) {               // w1T [c<1024][k<256]
        const int j = i - 229376, c = j >> 8, k = j & 255;
        w1T[j] = __float2half(w1[k * 1024 + c]);
    } else if (i < 753664) {               // w2T [c<256][k<1024]
        const int j = i - 491520, c = j >> 10, k = j & 1023;
        w2T[j] = __float2half(w2[k * 256 + c]);
    }
    if (i < 640) {
        bcat[i] = (i < 256) ? b_off[i] : (i < 384) ? b_attn[i - 256] : b_val[i - 384];
    }
}

// ---------------- cvt: qh = half(src+pos), srch = half(src) ----------------
__global__ __launch_bounds__(256) void cvt_k(const float* __restrict__ src,
                                             const float* __restrict__ pos,
                                             __half* __restrict__ qh,
                                             __half* __restrict__ srch) {
    const size_t i = (size_t)blockIdx.x * 256 + threadIdx.x;   // 4 elems each
    float4 s = *(const float4*)&src[i * 4];
    float4 p = *(const float4*)&pos[i * 4];
    union { __half2 h[2]; uint2 u; } Q, S;
    Q.h[0] = __floats2half2_rn(s.x + p.x, s.y + p.y);
    Q.h[1] = __floats2half2_rn(s.z + p.z, s.w + p.w);
    S.h[0] = __floats2half2_rn(s.x, s.y);
    S.h[1] = __floats2half2_rn(s.z, s.w);
    *(uint2*)&qh[i * 4]   = Q.u;
    *(uint2*)&srch[i * 4] = S.u;
}

// ---------------- whole-K fp16 MFMA GEMM ----------------
// C[M,N] = A[M,K] @ Bt[N,K]^T + bias. Tile BM x BN, K staged in KC=256 chunks
// ENTIRELY in LDS via global_load_lds (no staging VGPRs, one latency exposure
// per chunk), then one barrier and an uninterrupted MFMA burst.
// LDS layout linear [rows][256] halfs (512B rows); bank conflicts killed by the
// both-sides XOR swizzle (rule 21): global source column-chunk ^= (row&7) at
// fill, ds_read chunk ^= (fr&7) at read (row&7 == fr&7 for fragment rows).
// A-select: bx*BN < colSwitch -> Aq (q = src+pos), else Av.
// OMODE: 0 = f32 out; 2 = relu + f16 out; 3 = split f32 / f16-at-(col-colSwitch).
template <int BM, int BN, int OMODE>
__global__ __launch_bounds__(256) void hgemm_k(const __half* __restrict__ Aq,
                                               const __half* __restrict__ Av,
                                               const __half* __restrict__ Bt,
                                               const float* __restrict__ bias,
                                               float* __restrict__ Cf,
                                               __half* __restrict__ Ch,
                                               int NnF, int NnH, int K, int colSwitch) {
    constexpr int KC = 256;
    constexpr int MR = BM / 32;           // 2x2 wave grid; frags per wave row
    constexpr int NR = BN / 32;
    __shared__ __half As[BM][KC];
    __shared__ __half Bs[BN][KC];

    const int nbx = gridDim.x;
    const int tile = swz8(blockIdx.y * nbx + blockIdx.x, nbx * gridDim.y);
    const int bx = tile % nbx, by = tile / nbx;

    const int tid = threadIdx.x;
    const int lane = tid & 63;
    const int wave = tid >> 6;
    const int wr = (wave >> 1) * (BM / 2);
    const int wc = (wave & 1) * (BN / 2);

    const __half* __restrict__ Ah = (bx * BN < colSwitch) ? Aq : Av;

    // fill-side lane constants: lane rl=lane>>5 (row parity), ck=lane&31 (chunk)
    const int rl = lane >> 5, ck = lane & 31;
    const int xm = (2 * wave + rl) & 7;            // row&7 of this lane's rows
    const int colx = ((ck ^ xm) << 3);             // pre-swizzled source col (halfs)
    const __half* Ap = Ah + (size_t)(by * BM + 2 * wave + rl) * K + colx;
    const __half* Bp = Bt + (size_t)(bx * BN + 2 * wave + rl) * K + colx;

    // read-side lane constants
    const int fr = lane & 15;          // fragment row within 16
    const int hi = lane >> 4;          // k-subchunk 0..3
    const int xr = fr & 7;

    f32x4 acc[MR][NR];
#pragma unroll
    for (int m = 0; m < MR; ++m)
#pragma unroll
        for (int n = 0; n < NR; ++n) acc[m][n] = (f32x4){0.f, 0.f, 0.f, 0.f};

    for (int kc = 0; kc < K; kc += KC) {
        if (kc) __syncthreads();       // previous chunk's reads done
        // fill: each wave-issue writes 2 rows (64 lanes x 16B = 1KB)
#pragma unroll
        for (int j = 0; j < BM / 8; ++j)
            gload_lds16(Ap + ((size_t)(8 * j) * K + kc), &As[2 * wave + 8 * j][0]);
#pragma unroll
        for (int j = 0; j < BN / 8; ++j)
            gload_lds16(Bp + ((size_t)(8 * j) * K + kc), &Bs[2 * wave + 8 * j][0]);
        __syncthreads();               // compiler drains vmcnt before barrier

        const char* Ab = (const char*)&As[0][0];
        const char* Bb = (const char*)&Bs[0][0];
#pragma unroll
        for (int kk = 0; kk < KC / 32; ++kk) {
            const int cb = (kk << 2) + hi;
            const int co = ((cb ^ xr) << 4);
            f16x8 af[MR], bf[NR];
#pragma unroll
            for (int m = 0; m < MR; ++m)
                af[m] = *(const f16x8*)(Ab + (wr + m * 16 + fr) * (KC * 2) + co);
#pragma unroll
            for (int n = 0; n < NR; ++n)
                bf[n] = *(const f16x8*)(Bb + (wc + n * 16 + fr) * (KC * 2) + co);
#pragma unroll
            for (int m = 0; m < MR; ++m)
#pragma unroll
                for (int n = 0; n < NR; ++n)
                    acc[m][n] = __builtin_amdgcn_mfma_f32_16x16x32_f16(af[m], bf[n], acc[m][n], 0, 0, 0);
        }
    }

    // C/D layout (m89): col = lane&15, row = (lane>>4)*4 + reg
    const int rowb = by * BM + wr + hi * 4;
    const int colb = bx * BN + wc + fr;
    float bn[NR];
#pragma unroll
    for (int n = 0; n < NR; ++n) bn[n] = bias[colb + n * 16];
    const bool vhalf = (OMODE == 2) || (OMODE == 3 && bx * BN >= colSwitch);
    const int colh = (OMODE == 3) ? (colb - colSwitch) : colb;
#pragma unroll
    for (int m = 0; m < MR; ++m) {
#pragma unroll
        for (int r = 0; r < 4; ++r) {
            const int row = rowb + m * 16 + r;
#pragma unroll
            for (int n = 0; n < NR; ++n) {
                float v = acc[m][n][r] + bn[n];
                if (OMODE == 2) v = fmaxf(v, 0.f);
                if (vhalf) Ch[(size_t)row * NnH + colh + n * 16] = __float2half(v);
                else       Cf[(size_t)row * NnF + colb + n * 16] = v;
            }
        }
    }
}

// ---------------- MSDA: two-phase (descriptor prep in LDS, then fp16 gather) ----
__global__ __launch_bounds__(256) void msda_kernel(const float* __restrict__ C1a,
                                                   const __half* __restrict__ Vh,
                                                   const float* __restrict__ refp,
                                                   __half* __restrict__ out) {
    __shared__ int      sOff[16][17][4];   // byte offsets into Vh (pos*512 + h*64)
    __shared__ unsigned sWh[16][17][4];    // packed half2(w, w)
    const int tid = threadIdx.x;
    const int gi = tid >> 4;           // (token,head) group 0..15
    const int si = tid & 15;
    const int tile = swz8(blockIdx.x, gridDim.x);   // NTOK/2 divisible by 8
    const int n = tile * 2 + (gi >> 3);
    const int h = gi & 7;
    const int b = n / LEN;

    // ---- phase 1: one lane per (l,p) sample computes softmax + corner descriptors
    {
        const int l = si >> 2, p = si & 3;
        const float lg = C1a[(size_t)n * 384 + 256 + h * 16 + si];
        float mx = lg;
#pragma unroll
        for (int m = 1; m < 16; m <<= 1) mx = fmaxf(mx, __shfl_xor(mx, m, 16));
        const float e = __expf(lg - mx);
        float sum = e;
#pragma unroll
        for (int m = 1; m < 16; m <<= 1) sum += __shfl_xor(sum, m, 16);
        const float aw = e / sum;

        const int Wi[4] = {64, 32, 16, 8};
        const int st[4] = {0, 4096, 5120, 5376};
        const int W = Wi[l];
        const float Wf = (float)W;
        const float rx = refp[((size_t)n * 4 + l) * 2 + 0];
        const float ry = refp[((size_t)n * 4 + l) * 2 + 1];
        const float2 oxy = *(const float2*)&C1a[(size_t)n * 384 + (((h * 4 + l) * 4 + p) * 2)];
        // match reference op order: loc = ref + off/W ; px = loc*W - 0.5
        const float lx = rx + oxy.x / Wf;
        const float ly = ry + oxy.y / Wf;
        const float px = lx * Wf - 0.5f;
        const float py = ly * Wf - 0.5f;
        const float x0f = floorf(px), y0f = floorf(py);
        const float wx1 = px - x0f, wy1 = py - y0f;
        const int x0 = (int)x0f, y0 = (int)y0f;
#pragma unroll
        for (int c = 0; c < 4; ++c) {
            const int dx = c & 1, dy = c >> 1;
            const int ix = x0 + dx, iy = y0 + dy;
            const float wgt = (dx ? wx1 : 1.f - wx1) * (dy ? wy1 : 1.f - wy1);
            const bool valid = (ix >= 0) && (ix < W) && (iy >= 0) && (iy < W);
            const int ixc = min(max(ix, 0), W - 1);
            const int iyc = min(max(iy, 0), W - 1);
            const int pos = st[l] + iyc * W + ixc;
            sOff[gi][si][c] = ((b * LEN + pos) << 9) + (h << 6);   // BYTE offset
            const float wa = valid ? (aw * wgt) : 0.f;
            const unsigned wu = (unsigned)__half_as_ushort(__float2half_rn(wa));
            sWh[gi][si][c] = wu | (wu << 16);
        }
    }
    __syncthreads();

    // ---- phase 2: 16 corners x 8 channels per lane, all packed fp16
    const int cbyte = (si & 3) * 16;    // channel-octet byte offset within h-slice
    const int sb = (si >> 2) * 4;       // first sample of this lane's block
    __half2 acc0 = u2h2(0), acc1 = u2h2(0), acc2 = u2h2(0), acc3 = u2h2(0);
    const char* Vb = (const char*)Vh;
#pragma unroll
    for (int t = 0; t < 4; ++t) {
        const int s = sb + t;
        const int4  off = *(const int4*)&sOff[gi][s][0];
        const uint4 wq  = *(const uint4*)&sWh[gi][s][0];
        union { uint4 u; __half2 h2[4]; } v0, v1, v2, v3;
        v0.u = *(const uint4*)(Vb + off.x + cbyte);
        v1.u = *(const uint4*)(Vb + off.y + cbyte);
        v2.u = *(const uint4*)(Vb + off.z + cbyte);
        v3.u = *(const uint4*)(Vb + off.w + cbyte);
        const __half2 w0 = u2h2(wq.x), w1 = u2h2(wq.y), w2 = u2h2(wq.z), w3 = u2h2(wq.w);
        acc0 = __hfma2(v0.h2[0], w0, acc0);
        acc1 = __hfma2(v0.h2[1], w0, acc1);
        acc2 = __hfma2(v0.h2[2], w0, acc2);
        acc3 = __hfma2(v0.h2[3], w0, acc3);
        acc0 = __hfma2(v1.h2[0], w1, acc0);
        acc1 = __hfma2(v1.h2[1], w1, acc1);
        acc2 = __hfma2(v1.h2[2], w1, acc2);
        acc3 = __hfma2(v1.h2[3], w1, acc3);
        acc0 = __hfma2(v2.h2[0], w2, acc0);
        acc1 = __hfma2(v2.h2[1], w2, acc1);
        acc2 = __hfma2(v2.h2[2], w2, acc2);
        acc3 = __hfma2(v2.h2[3], w2, acc3);
        acc0 = __hfma2(v3.h2[0], w3, acc0);
        acc1 = __hfma2(v3.h2[1], w3, acc1);
        acc2 = __hfma2(v3.h2[2], w3, acc2);
        acc3 = __hfma2(v3.h2[3], w3, acc3);
    }
    // promote to f32, then reduce across the 4 corner-blocks (si^4, si^8)
    float f0 = __low2float(acc0), f1 = __high2float(acc0);
    float f2 = __low2float(acc1), f3 = __high2float(acc1);
    float f4 = __low2float(acc2), f5 = __high2float(acc2);
    float f6 = __low2float(acc3), f7 = __high2float(acc3);
#pragma unroll
    for (int m = 4; m <= 8; m <<= 1) {
        f0 += __shfl_xor(f0, m, 64);
        f1 += __shfl_xor(f1, m, 64);
        f2 += __shfl_xor(f2, m, 64);
        f3 += __shfl_xor(f3, m, 64);
        f4 += __shfl_xor(f4, m, 64);
        f5 += __shfl_xor(f5, m, 64);
        f6 += __shfl_xor(f6, m, 64);
        f7 += __shfl_xor(f7, m, 64);
    }
    if (si < 4) {
        union { __half2 h2[4]; uint4 u; } O;
        O.h2[0] = __floats2half2_rn(f0, f1);
        O.h2[1] = __floats2half2_rn(f2, f3);
        O.h2[2] = __floats2half2_rn(f4, f5);
        O.h2[3] = __floats2half2_rn(f6, f7);
        *(uint4*)&out[(size_t)n * 256 + h * 32 + si * 8] = O.u;
    }
}

// ---------------- LayerNorm (wave per token): O = LN(Y + R) * g + b ----------------
template <bool WH>
__global__ __launch_bounds__(256) void ln_kernel(const float* __restrict__ Y,
                                                 const float* __restrict__ R,
                                                 const float* __restrict__ gm,
                                                 const float* __restrict__ bt,
                                                 float* __restrict__ O,
                                                 __half* __restrict__ OH) {
    const int wave = threadIdx.x >> 6, lane = threadIdx.x & 63;
    const int n = blockIdx.x * 4 + wave;
    const size_t base = (size_t)n * 256 + lane * 4;
    float4 y = *(const float4*)&Y[base];
    float4 r = *(const float4*)&R[base];
    float4 v = f4_add(y, r);
    float s = v.x + v.y + v.z + v.w;
#pragma unroll
    for (int m = 1; m < 64; m <<= 1) s += __shfl_xor(s, m, 64);
    const float mean = s * (1.f / 256.f);
    const float dx = v.x - mean, dy = v.y - mean, dz = v.z - mean, dw = v.w - mean;
    float ss = dx * dx + dy * dy + dz * dz + dw * dw;
#pragma unroll
    for (int m = 1; m < 64; m <<= 1) ss += __shfl_xor(ss, m, 64);
    const float rstd = rsqrtf(ss * (1.f / 256.f) + LEPS);
    const float4 g4 = *(const float4*)&gm[lane * 4];
    const float4 b4 = *(const float4*)&bt[lane * 4];
    float4 o;
    o.x = dx * rstd * g4.x + b4.x;
    o.y = dy * rstd * g4.y + b4.y;
    o.z = dz * rstd * g4.z + b4.z;
    o.w = dw * rstd * g4.w + b4.w;
    *(float4*)&O[base] = o;
    if (WH) {
        union { __half2 h[2]; uint2 u; } Hh;
        Hh.h[0] = __floats2half2_rn(o.x, o.y);
        Hh.h[1] = __floats2half2_rn(o.z, o.w);
        *(uint2*)&OH[base] = Hh.u;
    }
}

// ---------------- launch ----------------
extern "C" void kernel_launch(void* const* d_in, const int* in_sizes, int n_in,
                              void* d_out, int out_size, void* d_ws, size_t ws_size,
                              hipStream_t stream) {
    const float* src   = (const float*)d_in[0];
    const float* pos   = (const float*)d_in[1];
    const float* refp  = (const float*)d_in[2];
    const float* w_off  = (const float*)d_in[6];
    const float* b_off  = (const float*)d_in[7];
    const float* w_attn = (const float*)d_in[8];
    const float* b_attn = (const float*)d_in[9];
    const float* w_val  = (const float*)d_in[10];
    const float* b_val  = (const float*)d_in[11];
    const float* w_out  = (const float*)d_in[12];
    const float* b_out  = (const float*)d_in[13];
    const float* g1     = (const float*)d_in[14];
    const float* be1    = (const float*)d_in[15];
    const float* w1     = (const float*)d_in[16];
    const float* b1     = (const float*)d_in[17];
    const float* w2     = (const float*)d_in[18];
    const float* b2     = (const float*)d_in[19];
    const float* g2     = (const float*)d_in[20];
    const float* be2    = (const float*)d_in[21];

    float* ws = (float*)d_ws;
    // workspace layout (float offsets); total ~39.4M floats ~= 158 MB
    float*  C1a   = ws + 0;                       // [N,384] f32 off|logits; ybuf alias
    __half* Vh    = (__half*)(ws + 8355840);      // [N,256] f16 value
    __half* msdah = (__half*)(ws + 11141120);     // [N,256] f16
    float*  xbuf  = ws + 13926400;                // [N,256] f32
    __half* xh    = (__half*)(ws + 19496960);     // [N,256] f16
    __half* hh    = (__half*)(ws + 22282240);     // [N,1024] f16
    __half* qh    = (__half*)(ws + 33423360);     // [N,256] f16
    __half* srch  = (__half*)(ws + 36208640);     // [N,256] f16
    __half* WcatT = (__half*)(ws + 38993920);     // [640][256] f16
    __half* woutT = (__half*)(ws + 39075840);     // [256][256] f16
    __half* w1T   = (__half*)(ws + 39108608);     // [1024][256] f16
    __half* w2T   = (__half*)(ws + 39239680);     // [256][1024] f16
    float*  bcat  = ws + 39370752;                // [640] f32
    float*  ybuf  = C1a;                          // C1a dead after msda

    pack_k<<<2944, 256, 0, stream>>>(w_off, w_attn, w_val, b_off, b_attn, b_val,
                                     w_out, w1, w2, WcatT, woutT, w1T, w2T, bcat);
    cvt_k<<<5440, 256, 0, stream>>>(src, pos, qh, srch);

    // GEMM1: [N,640] = (qh | srch) @ Wcat + bcat ; cols<384 -> C1a f32, else Vh f16
    hgemm_k<128, 128, 3><<<dim3(5, 170), 256, 0, stream>>>(
        qh, srch, WcatT, bcat, C1a, Vh, 384, 256, 256, 384);

    msda_kernel<<<NTOK / 2, 256, 0, stream>>>(C1a, Vh, refp, msdah);

    // ybuf = msda @ w_out + b_out  (64x64 tiles: 1360 blocks, 64KB LDS)
    hgemm_k<64, 64, 0><<<dim3(4, 340), 256, 0, stream>>>(
        msdah, msdah, woutT, b_out, ybuf, nullptr, 256, 256, 256, 1 << 30);

    // x = LN(ybuf + src) -> xbuf (f32) and xh (f16)
    ln_kernel<true><<<NTOK / 4, 256, 0, stream>>>(ybuf, src, g1, be1, xbuf, xh);

    // hh = relu(x @ w1 + b1)  (f16)
    hgemm_k<128, 128, 2><<<dim3(8, 170), 256, 0, stream>>>(
        xh, xh, w1T, b1, nullptr, hh, 1024, 1024, 256, 1 << 30);

    // ybuf = hh @ w2 + b2  (K=1024: 4 chunks)
    hgemm_k<64, 64, 0><<<dim3(4, 340), 256, 0, stream>>>(
        hh, hh, w2T, b2, ybuf, nullptr, 256, 256, 1024, 1 << 30);

    // out = LN(ybuf + xbuf)
    ln_kernel<false><<<NTOK / 4, 256, 0, stream>>>(ybuf, xbuf, g2, be2, (float*)d_out, nullptr);
}

// Round 10
// 266.664 us; speedup vs baseline: 1.0722x; 1.0722x over previous
//
#include <hip/hip_runtime.h>
#include <hip/hip_fp16.h>
#include <math.h>

// Problem constants (fixed by the reference)
#define LEN   5440          // 64*64 + 32*32 + 16*16 + 8*8
#define NTOK  21760         // B(4) * LEN
#define DFF   1024
#define LEPS  1e-5f

typedef __attribute__((ext_vector_type(8))) _Float16 f16x8;
typedef __attribute__((ext_vector_type(4))) float f32x4;

__device__ __forceinline__ float4 f4_add(float4 a, float4 b) {
    return make_float4(a.x + b.x, a.y + b.y, a.z + b.z, a.w + b.w);
}

__device__ __forceinline__ __half2 u2h2(unsigned u) {
    union { unsigned u; __half2 h; } c; c.u = u; return c.h;
}

// async global->LDS, 16B per lane; LDS dest = wave-uniform base + lane*16.
__device__ __forceinline__ void gload_lds16(const void* g, void* l) {
    __builtin_amdgcn_global_load_lds(
        (const __attribute__((address_space(1))) unsigned int*)g,
        (__attribute__((address_space(3))) unsigned int*)l, 16, 0, 0);
}

// Bijective XCD-chunk swizzle (m204).
__device__ __forceinline__ int swz8(int lin, int nwg) {
    const int q = nwg >> 3, r = nwg & 7;
    const int x = lin & 7, j = lin >> 3;
    return (x < r ? x * (q + 1) : r * (q + 1) + (x - r) * q) + j;
}

// ---------------- pack: weights -> fp16, transposed to [N][K] ----------------
__global__ __launch_bounds__(256) void pack_k(const float* __restrict__ w_off,
                                              const float* __restrict__ w_attn,
                                              const float* __restrict__ w_val,
                                              const float* __restrict__ b_off,
                                              const float* __restrict__ b_attn,
                                              const float* __restrict__ b_val,
                                              const float* __restrict__ w_out,
                                              const float* __restrict__ w1,
                                              const float* __restrict__ w2,
                                              __half* __restrict__ WcatT,
                                              __half* __restrict__ woutT,
                                              __half* __restrict__ w1T,
                                              __half* __restrict__ w2T,
                                              float* __restrict__ bcat) {
    const int i = blockIdx.x * 256 + threadIdx.x;
    if (i < 163840) {                      // WcatT [c<640][k<256]
        const int c = i >> 8, k = i & 255;
        float v;
        if (c < 256)      v = w_off[k * 256 + c];
        else if (c < 384) v = w_attn[k * 128 + (c - 256)];
        else              v = w_val[k * 256 + (c - 384)];
        WcatT[i] = __float2half(v);
    } else if (i < 229376) {               // woutT [c<256][k<256]
        const int j = i - 163840, c = j >> 8, k = j & 255;
        woutT[j] = __float2half(w_out[k * 256 + c]);
    } else if (i < 491520) {               // w1T [c<1024][k<256]
        const int j = i - 229376, c = j >> 8, k = j & 255;
        w1T[j] = __float2half(w1[k * 1024 + c]);
    } else if (i < 753664) {               // w2T [c<256][k<1024]
        const int j = i - 491520, c = j >> 10, k = j & 1023;
        w2T[j] = __float2half(w2[k * 256 + c]);
    }
    if (i < 640) {
        bcat[i] = (i < 256) ? b_off[i] : (i < 384) ? b_attn[i - 256] : b_val[i - 384];
    }
}

// ---------------- cvt: qh = half(src+pos), srch = half(src) ----------------
__global__ __launch_bounds__(256) void cvt_k(const float* __restrict__ src,
                                             const float* __restrict__ pos,
                                             __half* __restrict__ qh,
                                             __half* __restrict__ srch) {
    const size_t i = (size_t)blockIdx.x * 256 + threadIdx.x;   // 4 elems each
    float4 s = *(const float4*)&src[i * 4];
    float4 p = *(const float4*)&pos[i * 4];
    union { __half2 h[2]; uint2 u; } Q, S;
    Q.h[0] = __floats2half2_rn(s.x + p.x, s.y + p.y);
    Q.h[1] = __floats2half2_rn(s.z + p.z, s.w + p.w);
    S.h[0] = __floats2half2_rn(s.x, s.y);
    S.h[1] = __floats2half2_rn(s.z, s.w);
    *(uint2*)&qh[i * 4]   = Q.u;
    *(uint2*)&srch[i * 4] = S.u;
}

// ---------------- whole-K fp16 MFMA GEMM (plain epilogue) ----------------
// C[M,N] = A[M,K] @ Bt[N,K]^T + bias. BM x BN tile, KC=256 chunks fully in LDS
// via global_load_lds; both-sides XOR swizzle (rule 21) kills read conflicts.
// OMODE: 0 = f32 out; 2 = relu + f16 out; 3 = split f32 / f16-at-(col-colSwitch).
template <int BM, int BN, int OMODE>
__global__ __launch_bounds__(256) void hgemm_k(const __half* __restrict__ Aq,
                                               const __half* __restrict__ Av,
                                               const __half* __restrict__ Bt,
                                               const float* __restrict__ bias,
                                               float* __restrict__ Cf,
                                               __half* __restrict__ Ch,
                                               int NnF, int NnH, int K, int colSwitch) {
    constexpr int KC = 256;
    constexpr int MR = BM / 32;
    constexpr int NR = BN / 32;
    __shared__ __half As[BM][KC];
    __shared__ __half Bs[BN][KC];

    const int nbx = gridDim.x;
    const int tile = swz8(blockIdx.y * nbx + blockIdx.x, nbx * gridDim.y);
    const int bx = tile % nbx, by = tile / nbx;

    const int tid = threadIdx.x;
    const int lane = tid & 63;
    const int wave = tid >> 6;
    const int wr = (wave >> 1) * (BM / 2);
    const int wc = (wave & 1) * (BN / 2);

    const __half* __restrict__ Ah = (bx * BN < colSwitch) ? Aq : Av;

    const int rl = lane >> 5, ck = lane & 31;
    const int xm = (2 * wave + rl) & 7;
    const int colx = ((ck ^ xm) << 3);
    const __half* Ap = Ah + (size_t)(by * BM + 2 * wave + rl) * K + colx;
    const __half* Bp = Bt + (size_t)(bx * BN + 2 * wave + rl) * K + colx;

    const int fr = lane & 15;
    const int hi = lane >> 4;
    const int xr = fr & 7;

    f32x4 acc[MR][NR];
#pragma unroll
    for (int m = 0; m < MR; ++m)
#pragma unroll
        for (int n = 0; n < NR; ++n) acc[m][n] = (f32x4){0.f, 0.f, 0.f, 0.f};

    for (int kc = 0; kc < K; kc += KC) {
        if (kc) __syncthreads();
#pragma unroll
        for (int j = 0; j < BM / 8; ++j)
            gload_lds16(Ap + ((size_t)(8 * j) * K + kc), &As[2 * wave + 8 * j][0]);
#pragma unroll
        for (int j = 0; j < BN / 8; ++j)
            gload_lds16(Bp + ((size_t)(8 * j) * K + kc), &Bs[2 * wave + 8 * j][0]);
        __syncthreads();

        const char* Ab = (const char*)&As[0][0];
        const char* Bb = (const char*)&Bs[0][0];
#pragma unroll
        for (int kk = 0; kk < KC / 32; ++kk) {
            const int cb = (kk << 2) + hi;
            const int co = ((cb ^ xr) << 4);
            f16x8 af[MR], bf[NR];
#pragma unroll
            for (int m = 0; m < MR; ++m)
                af[m] = *(const f16x8*)(Ab + (wr + m * 16 + fr) * (KC * 2) + co);
#pragma unroll
            for (int n = 0; n < NR; ++n)
                bf[n] = *(const f16x8*)(Bb + (wc + n * 16 + fr) * (KC * 2) + co);
#pragma unroll
            for (int m = 0; m < MR; ++m)
#pragma unroll
                for (int n = 0; n < NR; ++n)
                    acc[m][n] = __builtin_amdgcn_mfma_f32_16x16x32_f16(af[m], bf[n], acc[m][n], 0, 0, 0);
        }
    }

    const int rowb = by * BM + wr + hi * 4;
    const int colb = bx * BN + wc + fr;
    float bn[NR];
#pragma unroll
    for (int n = 0; n < NR; ++n) bn[n] = bias[colb + n * 16];
    const bool vhalf = (OMODE == 2) || (OMODE == 3 && bx * BN >= colSwitch);
    const int colh = (OMODE == 3) ? (colb - colSwitch) : colb;
#pragma unroll
    for (int m = 0; m < MR; ++m) {
#pragma unroll
        for (int r = 0; r < 4; ++r) {
            const int row = rowb + m * 16 + r;
#pragma unroll
            for (int n = 0; n < NR; ++n) {
                float v = acc[m][n][r] + bn[n];
                if (OMODE == 2) v = fmaxf(v, 0.f);
                if (vhalf) Ch[(size_t)row * NnH + colh + n * 16] = __float2half(v);
                else       Cf[(size_t)row * NnF + colb + n * 16] = v;
            }
        }
    }
}

// ---------------- whole-K GEMM + fused residual-LayerNorm ----------------
// O = LN(A @ Bt^T + bias + RES) * g + be. BM=64 x BN=256 (full row), KC=128.
// LDS 80KB -> 2 blocks/CU. Row stats: per-lane partials -> width-16 shuffle
// reduce -> 1KB LDS exchange (aliased into As) across the two column-waves.
// LN1MODE: write Of f32 + Oh f16 ; else Of f32 only.
template <int KTOT, bool LN1MODE>
__global__ __launch_bounds__(256) void hgemm_ln_k(const __half* __restrict__ A,
                                                  const __half* __restrict__ Bt,
                                                  const float* __restrict__ bias,
                                                  const float* __restrict__ RES,
                                                  const float* __restrict__ gm,
                                                  const float* __restrict__ be,
                                                  float* __restrict__ Of,
                                                  __half* __restrict__ Oh) {
    constexpr int KC = 128;
    __shared__ __half As[64][KC];     // 16KB (aliased as sRed in epilogue)
    __shared__ __half Bs[256][KC];    // 64KB

    const int by = swz8(blockIdx.x, gridDim.x);
    const int tid = threadIdx.x;
    const int lane = tid & 63;
    const int wave = tid >> 6;
    const int wr = (wave >> 1) * 32;     // wave row base (MR=2)
    const int wc = (wave & 1) * 128;     // wave col base (NR=8)

    // fill-side constants: 1KB per instr = 4 rows of 256B
    const int lrw = lane >> 4;           // row-in-quad 0..3
    const int u   = lane & 15;           // 16B unit in row
    const int x0 = u ^ lrw;              // row&7 = lrw   (base rows +0)
    const int x1 = u ^ (4 + lrw);        // row&7 = 4+lrw (base rows +4)
    const __half* pA0 = A + (size_t)(by * 64 + wave * 16 + lrw) * KTOT + (x0 << 3);
    const __half* pA1 = A + (size_t)(by * 64 + wave * 16 + 4 + lrw) * KTOT + (x1 << 3);
    const __half* pB0 = Bt + (size_t)(wave * 64 + lrw) * KTOT + (x0 << 3);
    const __half* pB1 = Bt + (size_t)(wave * 64 + 4 + lrw) * KTOT + (x1 << 3);

    const int fr = lane & 15;
    const int hi = lane >> 4;
    const int xr = fr & 7;

    f32x4 acc[2][8];
#pragma unroll
    for (int m = 0; m < 2; ++m)
#pragma unroll
        for (int n = 0; n < 8; ++n) acc[m][n] = (f32x4){0.f, 0.f, 0.f, 0.f};

    for (int kc = 0; kc < KTOT; kc += KC) {
        if (kc) __syncthreads();
        // A: 4 instrs/wave (16 rows), B: 16 instrs/wave (64 rows)
        gload_lds16(pA0 + kc, &As[wave * 16 + 0][0]);
        gload_lds16(pA1 + kc, &As[wave * 16 + 4][0]);
        gload_lds16(pA0 + kc + (size_t)8 * KTOT, &As[wave * 16 + 8][0]);
        gload_lds16(pA1 + kc + (size_t)8 * KTOT, &As[wave * 16 + 12][0]);
#pragma unroll
        for (int j = 0; j < 8; ++j) {
            gload_lds16(pB0 + kc + (size_t)(8 * j) * KTOT, &Bs[wave * 64 + 8 * j + 0][0]);
            gload_lds16(pB1 + kc + (size_t)(8 * j) * KTOT, &Bs[wave * 64 + 8 * j + 4][0]);
        }
        __syncthreads();

        const char* Ab = (const char*)&As[0][0];
        const char* Bb = (const char*)&Bs[0][0];
#pragma unroll
        for (int kk = 0; kk < 4; ++kk) {
            const int co = (((kk << 2) + hi) ^ xr) << 4;
            f16x8 af[2], bf[8];
#pragma unroll
            for (int m = 0; m < 2; ++m)
                af[m] = *(const f16x8*)(Ab + (wr + m * 16 + fr) * (KC * 2) + co);
#pragma unroll
            for (int n = 0; n < 8; ++n)
                bf[n] = *(const f16x8*)(Bb + (wc + n * 16 + fr) * (KC * 2) + co);
#pragma unroll
            for (int m = 0; m < 2; ++m)
#pragma unroll
                for (int n = 0; n < 8; ++n)
                    acc[m][n] = __builtin_amdgcn_mfma_f32_16x16x32_f16(af[m], bf[n], acc[m][n], 0, 0, 0);
        }
    }

    // -------- fused LN epilogue --------
    const int rowl = wr + hi * 4;            // local row base (0..63)
    const int colb = wc + fr;                // column (0..255)
    float bn[8], gw[8], bw[8];
#pragma unroll
    for (int n = 0; n < 8; ++n) {
        bn[n] = bias[colb + n * 16];
        gw[n] = gm[colb + n * 16];
        bw[n] = be[colb + n * 16];
    }

    // v = acc + bias + residual (in place); per-lane row partial sums
    float s1[2][4], s2[2][4];
#pragma unroll
    for (int m = 0; m < 2; ++m) {
#pragma unroll
        for (int r = 0; r < 4; ++r) {
            const float* resp = RES + (size_t)(by * 64 + rowl + m * 16 + r) * 256 + colb;
            float a1 = 0.f, a2 = 0.f;
#pragma unroll
            for (int n = 0; n < 8; ++n) {
                float v = acc[m][n][r] + bn[n] + resp[n * 16];
                acc[m][n][r] = v;
                a1 += v;
                a2 = fmaf(v, v, a2);
            }
            s1[m][r] = a1;
            s2[m][r] = a2;
        }
    }
    // reduce across the 16 fr-lanes (width-16 butterfly)
#pragma unroll
    for (int d = 1; d < 16; d <<= 1) {
#pragma unroll
        for (int m = 0; m < 2; ++m)
#pragma unroll
            for (int r = 0; r < 4; ++r) {
                s1[m][r] += __shfl_xor(s1[m][r], d, 16);
                s2[m][r] += __shfl_xor(s2[m][r], d, 16);
            }
    }
    // exchange across the two column-wave halves via 1KB LDS (alias into As)
    float* sRed = (float*)&As[0][0];         // [2 halves][64 rows][2 stats]
    __syncthreads();                         // all As/Bs reads done
    if (fr == 0) {
#pragma unroll
        for (int m = 0; m < 2; ++m)
#pragma unroll
            for (int r = 0; r < 4; ++r) {
                const int lr = rowl + m * 16 + r;
                sRed[((wave & 1) * 64 + lr) * 2 + 0] = s1[m][r];
                sRed[((wave & 1) * 64 + lr) * 2 + 1] = s2[m][r];
            }
    }
    __syncthreads();
#pragma unroll
    for (int m = 0; m < 2; ++m) {
#pragma unroll
        for (int r = 0; r < 4; ++r) {
            const int lr = rowl + m * 16 + r;
            const float t1 = s1[m][r] + sRed[(((wave & 1) ^ 1) * 64 + lr) * 2 + 0];
            const float t2 = s2[m][r] + sRed[(((wave & 1) ^ 1) * 64 + lr) * 2 + 1];
            const float mean = t1 * (1.f / 256.f);
            const float rstd = rsqrtf(t2 * (1.f / 256.f) - mean * mean + LEPS);
            const size_t ro = (size_t)(by * 64 + lr) * 256 + colb;
#pragma unroll
            for (int n = 0; n < 8; ++n) {
                const float o = (acc[m][n][r] - mean) * rstd * gw[n] + bw[n];
                Of[ro + n * 16] = o;
                if (LN1MODE) Oh[ro + n * 16] = __float2half(o);
            }
        }
    }
}

// ---------------- MSDA: two-phase (descriptor prep in LDS, then fp16 gather) ----
__global__ __launch_bounds__(256) void msda_kernel(const float* __restrict__ C1a,
                                                   const __half* __restrict__ Vh,
                                                   const float* __restrict__ refp,
                                                   __half* __restrict__ out) {
    __shared__ int      sOff[16][17][4];   // byte offsets into Vh (pos*512 + h*64)
    __shared__ unsigned sWh[16][17][4];    // packed half2(w, w)
    const int tid = threadIdx.x;
    const int gi = tid >> 4;           // (token,head) group 0..15
    const int si = tid & 15;
    const int tile = swz8(blockIdx.x, gridDim.x);   // NTOK/2 divisible by 8
    const int n = tile * 2 + (gi >> 3);
    const int h = gi & 7;
    const int b = n / LEN;

    // ---- phase 1: one lane per (l,p) sample computes softmax + corner descriptors
    {
        const int l = si >> 2, p = si & 3;
        const float lg = C1a[(size_t)n * 384 + 256 + h * 16 + si];
        float mx = lg;
#pragma unroll
        for (int m = 1; m < 16; m <<= 1) mx = fmaxf(mx, __shfl_xor(mx, m, 16));
        const float e = __expf(lg - mx);
        float sum = e;
#pragma unroll
        for (int m = 1; m < 16; m <<= 1) sum += __shfl_xor(sum, m, 16);
        const float aw = e / sum;

        const int Wi[4] = {64, 32, 16, 8};
        const int st[4] = {0, 4096, 5120, 5376};
        const int W = Wi[l];
        const float Wf = (float)W;
        const float rx = refp[((size_t)n * 4 + l) * 2 + 0];
        const float ry = refp[((size_t)n * 4 + l) * 2 + 1];
        const float2 oxy = *(const float2*)&C1a[(size_t)n * 384 + (((h * 4 + l) * 4 + p) * 2)];
        // match reference op order: loc = ref + off/W ; px = loc*W - 0.5
        const float lx = rx + oxy.x / Wf;
        const float ly = ry + oxy.y / Wf;
        const float px = lx * Wf - 0.5f;
        const float py = ly * Wf - 0.5f;
        const float x0f = floorf(px), y0f = floorf(py);
        const float wx1 = px - x0f, wy1 = py - y0f;
        const int x0 = (int)x0f, y0 = (int)y0f;
#pragma unroll
        for (int c = 0; c < 4; ++c) {
            const int dx = c & 1, dy = c >> 1;
            const int ix = x0 + dx, iy = y0 + dy;
            const float wgt = (dx ? wx1 : 1.f - wx1) * (dy ? wy1 : 1.f - wy1);
            const bool valid = (ix >= 0) && (ix < W) && (iy >= 0) && (iy < W);
            const int ixc = min(max(ix, 0), W - 1);
            const int iyc = min(max(iy, 0), W - 1);
            const int pos = st[l] + iyc * W + ixc;
            sOff[gi][si][c] = ((b * LEN + pos) << 9) + (h << 6);   // BYTE offset
            const float wa = valid ? (aw * wgt) : 0.f;
            const unsigned wu = (unsigned)__half_as_ushort(__float2half_rn(wa));
            sWh[gi][si][c] = wu | (wu << 16);
        }
    }
    __syncthreads();

    // ---- phase 2: 16 corners x 8 channels per lane, all packed fp16
    const int cbyte = (si & 3) * 16;    // channel-octet byte offset within h-slice
    const int sb = (si >> 2) * 4;       // first sample of this lane's block
    __half2 acc0 = u2h2(0), acc1 = u2h2(0), acc2 = u2h2(0), acc3 = u2h2(0);
    const char* Vb = (const char*)Vh;
#pragma unroll
    for (int t = 0; t < 4; ++t) {
        const int s = sb + t;
        const int4  off = *(const int4*)&sOff[gi][s][0];
        const uint4 wq  = *(const uint4*)&sWh[gi][s][0];
        union { uint4 u; __half2 h2[4]; } v0, v1, v2, v3;
        v0.u = *(const uint4*)(Vb + off.x + cbyte);
        v1.u = *(const uint4*)(Vb + off.y + cbyte);
        v2.u = *(const uint4*)(Vb + off.z + cbyte);
        v3.u = *(const uint4*)(Vb + off.w + cbyte);
        const __half2 w0 = u2h2(wq.x), w1 = u2h2(wq.y), w2 = u2h2(wq.z), w3 = u2h2(wq.w);
        acc0 = __hfma2(v0.h2[0], w0, acc0);
        acc1 = __hfma2(v0.h2[1], w0, acc1);
        acc2 = __hfma2(v0.h2[2], w0, acc2);
        acc3 = __hfma2(v0.h2[3], w0, acc3);
        acc0 = __hfma2(v1.h2[0], w1, acc0);
        acc1 = __hfma2(v1.h2[1], w1, acc1);
        acc2 = __hfma2(v1.h2[2], w1, acc2);
        acc3 = __hfma2(v1.h2[3], w1, acc3);
        acc0 = __hfma2(v2.h2[0], w2, acc0);
        acc1 = __hfma2(v2.h2[1], w2, acc1);
        acc2 = __hfma2(v2.h2[2], w2, acc2);
        acc3 = __hfma2(v2.h2[3], w2, acc3);
        acc0 = __hfma2(v3.h2[0], w3, acc0);
        acc1 = __hfma2(v3.h2[1], w3, acc1);
        acc2 = __hfma2(v3.h2[2], w3, acc2);
        acc3 = __hfma2(v3.h2[3], w3, acc3);
    }
    // promote to f32, then reduce across the 4 corner-blocks (si^4, si^8)
    float f0 = __low2float(acc0), f1 = __high2float(acc0);
    float f2 = __low2float(acc1), f3 = __high2float(acc1);
    float f4 = __low2float(acc2), f5 = __high2float(acc2);
    float f6 = __low2float(acc3), f7 = __high2float(acc3);
#pragma unroll
    for (int m = 4; m <= 8; m <<= 1) {
        f0 += __shfl_xor(f0, m, 64);
        f1 += __shfl_xor(f1, m, 64);
        f2 += __shfl_xor(f2, m, 64);
        f3 += __shfl_xor(f3, m, 64);
        f4 += __shfl_xor(f4, m, 64);
        f5 += __shfl_xor(f5, m, 64);
        f6 += __shfl_xor(f6, m, 64);
        f7 += __shfl_xor(f7, m, 64);
    }
    if (si < 4) {
        union { __half2 h2[4]; uint4 u; } O;
        O.h2[0] = __floats2half2_rn(f0, f1);
        O.h2[1] = __floats2half2_rn(f2, f3);
        O.h2[2] = __floats2half2_rn(f4, f5);
        O.h2[3] = __floats2half2_rn(f6, f7);
        *(uint4*)&out[(size_t)n * 256 + h * 32 + si * 8] = O.u;
    }
}

// ---------------- launch ----------------
extern "C" void kernel_launch(void* const* d_in, const int* in_sizes, int n_in,
                              void* d_out, int out_size, void* d_ws, size_t ws_size,
                              hipStream_t stream) {
    const float* src   = (const float*)d_in[0];
    const float* pos   = (const float*)d_in[1];
    const float* refp  = (const float*)d_in[2];
    const float* w_off  = (const float*)d_in[6];
    const float* b_off  = (const float*)d_in[7];
    const float* w_attn = (const float*)d_in[8];
    const float* b_attn = (const float*)d_in[9];
    const float* w_val  = (const float*)d_in[10];
    const float* b_val  = (const float*)d_in[11];
    const float* w_out  = (const float*)d_in[12];
    const float* b_out  = (const float*)d_in[13];
    const float* g1     = (const float*)d_in[14];
    const float* be1    = (const float*)d_in[15];
    const float* w1     = (const float*)d_in[16];
    const float* b1     = (const float*)d_in[17];
    const float* w2     = (const float*)d_in[18];
    const float* b2     = (const float*)d_in[19];
    const float* g2     = (const float*)d_in[20];
    const float* be2    = (const float*)d_in[21];

    float* ws = (float*)d_ws;
    // workspace layout (float offsets); total ~33.8M floats ~= 135 MB
    float*  C1a   = ws + 0;                       // [N,384] f32 off|logits
    __half* Vh    = (__half*)(ws + 8355840);      // [N,256] f16 value
    __half* msdah = (__half*)(ws + 11141120);     // [N,256] f16
    float*  xbuf  = ws + 13926400;                // [N,256] f32 (LN1 out)
    __half* xh    = (__half*)(ws + 19496960);     // [N,256] f16 (LN1 out)
    __half* hh    = (__half*)(ws + 22282240);     // [N,1024] f16
    __half* qh    = (__half*)(ws + 22282240);     // alias hh (dead before FFN1)
    __half* srch  = (__half*)(ws + 13926400);     // alias xbuf (dead before LN1)
    __half* WcatT = (__half*)(ws + 33423360);     // [640][256] f16
    __half* woutT = (__half*)(ws + 33505280);     // [256][256] f16
    __half* w1T   = (__half*)(ws + 33538048);     // [1024][256] f16
    __half* w2T   = (__half*)(ws + 33669120);     // [256][1024] f16
    float*  bcat  = ws + 33800192;                // [640] f32

    pack_k<<<2944, 256, 0, stream>>>(w_off, w_attn, w_val, b_off, b_attn, b_val,
                                     w_out, w1, w2, WcatT, woutT, w1T, w2T, bcat);
    cvt_k<<<5440, 256, 0, stream>>>(src, pos, qh, srch);

    // GEMM1: [N,640] = (qh | srch) @ Wcat + bcat ; cols<384 -> C1a f32, else Vh f16
    hgemm_k<128, 128, 3><<<dim3(5, 170), 256, 0, stream>>>(
        qh, srch, WcatT, bcat, C1a, Vh, 384, 256, 256, 384);

    msda_kernel<<<NTOK / 2, 256, 0, stream>>>(C1a, Vh, refp, msdah);

    // x = LN(msda @ w_out + b_out + src) -> xbuf f32 + xh f16   (fused)
    hgemm_ln_k<256, true><<<340, 256, 0, stream>>>(
        msdah, woutT, b_out, src, g1, be1, xbuf, xh);

    // hh = relu(x @ w1 + b1)  (f16)
    hgemm_k<128, 128, 2><<<dim3(8, 170), 256, 0, stream>>>(
        xh, xh, w1T, b1, nullptr, hh, 1024, 1024, 256, 1 << 30);

    // out = LN(hh @ w2 + b2 + xbuf)   (fused, f32 out)
    hgemm_ln_k<1024, false><<<340, 256, 0, stream>>>(
        hh, w2T, b2, xbuf, g2, be2, (float*)d_out, nullptr);
}